// Round 6
// baseline (228.475 us; speedup 1.0000x reference)
//
#include <hip/hip_runtime.h>
#include <math.h>

#define NN 2048
#define PP 4096
#define DD 128
#define SS 150
#define THR 204
#define CAP 320

typedef float f32x4 __attribute__((ext_vector_type(4)));
typedef short s16x8 __attribute__((ext_vector_type(8)));

// ws layout (float offsets)
#define OFF_POOLN 0          // 4096*128 f32 normalized pool
#define OFF_WTT   524288     // 16384 f32 (W^T, [k][d])
#define OFF_PROJ  540672     // 4096*128 f32 = z_pool @ W^T
#define OFF_NEG   1064960
#define OFF_REFL  1069056
#define OFF_POSD  1073152
#define OFF_TOPI  1077248    // 4096*204 ints
#define OFF_POOLB 1912832    // 4096*128 bf16 (131072 floats)

// ---------------- prep: normalize pool rows -> fp32 + bf16 ----------------
__global__ void prep_norm(const float* __restrict__ z1, const float* __restrict__ z2,
                          float* __restrict__ pool_n, unsigned short* __restrict__ poolb) {
    int b = blockIdx.x;          // pool row 0..4095
    int l = threadIdx.x;         // 0..63
    const float* src = (b < NN) ? z1 + (size_t)b * DD : z2 + (size_t)(b - NN) * DD;
    float2 v = *(const float2*)(src + 2 * l);
    float ss = v.x * v.x + v.y * v.y;
    #pragma unroll
    for (int mask = 1; mask < 64; mask <<= 1) ss += __shfl_xor(ss, mask);
    float inv = 1.0f / fmaxf(sqrtf(ss), 1e-12f);
    float2 nv; nv.x = v.x * inv; nv.y = v.y * inv;
    *(float2*)(pool_n + (size_t)b * DD + 2 * l) = nv;
    unsigned ux = __float_as_uint(nv.x); ux = (ux + 0x7FFFu + ((ux >> 16) & 1u)) >> 16;
    unsigned uy = __float_as_uint(nv.y); uy = (uy + 0x7FFFu + ((uy >> 16) & 1u)) >> 16;
    ((unsigned*)poolb)[(size_t)b * 64 + l] = ux | (uy << 16);
}

// ---------------- prep: transpose proj_w (fp32), layout [k][d] ----------------
__global__ void prep_wt(const float* __restrict__ pw, float* __restrict__ wtT) {
    int e = blockIdx.x * 256 + threadIdx.x;
    int k = e >> 7, d = e & 127;
    wtT[e] = pw[d * DD + k];
}

// ---------------- prep: P = z_pool @ W^T (no bias) ----------------
__global__ __launch_bounds__(256, 4) void prep_proj(
    const float* __restrict__ z1, const float* __restrict__ z2,
    const float* __restrict__ wtT, float* __restrict__ P) {
    __shared__ float z_sh[8][DD];
    int tid = threadIdx.x;
    int r0 = blockIdx.x * 8;
    for (int e = tid; e < 8 * DD; e += 256) {
        int rr = r0 + (e >> 7);
        z_sh[e >> 7][e & 127] = (rr < NN) ? z1[(size_t)rr * DD + (e & 127)]
                                          : z2[(size_t)(rr - NN) * DD + (e & 127)];
    }
    __syncthreads();
    int d = tid & 127, h = tid >> 7;
    float a0 = 0.f, a1 = 0.f, a2 = 0.f, a3 = 0.f;
    for (int k = 0; k < DD; k++) {
        float wv = wtT[k * DD + d];
        a0 += z_sh[4 * h + 0][k] * wv;
        a1 += z_sh[4 * h + 1][k] * wv;
        a2 += z_sh[4 * h + 2][k] * wv;
        a3 += z_sh[4 * h + 3][k] * wv;
    }
    P[(size_t)(r0 + 4 * h + 0) * DD + d] = a0;
    P[(size_t)(r0 + 4 * h + 1) * DD + d] = a1;
    P[(size_t)(r0 + 4 * h + 2) * DD + d] = a2;
    P[(size_t)(r0 + 4 * h + 3) * DD + d] = a3;
}

// order-preserving float->uint key (larger float => larger key)
__device__ __forceinline__ unsigned fkey(float v) {
    unsigned u = __float_as_uint(v);
    return u ^ (unsigned)(((int)u >> 31) | 0x80000000);
}

// ---------------- fused: MFMA gram (16 rows x 4096) + expsum + refl/posd + top-204 ----------------
// 512 thr / 8 waves; wave w owns cols [w*512, w*512+512); acc[32] f32x4 per lane (AGPR-native).
// value acc[ct][reg]: row = r0 + (l>>4)*4 + reg, col = w*512 + ct*16 + (l&15)   [verified layout]
__global__ __launch_bounds__(512, 2) void gramsel(
    const unsigned short* __restrict__ poolb,
    float* __restrict__ negsum, float* __restrict__ refl, float* __restrict__ posd,
    int* __restrict__ topidx) {
    __shared__ int hist[16][256];        // 16 KB
    __shared__ uint2 cand[16][CAP];      // 40 KB
    __shared__ float rowsum[16];
    __shared__ int rowB[16], rowCum[16], rowP16[16], cnt[16];

    int tid = threadIdx.x, w = tid >> 6, l = tid & 63;
    int lr = l & 15, rq4 = (l >> 4) * 4;
    int lk = (l >> 4) * 8;
    int r0 = blockIdx.x * 16;

    for (int e = tid; e < 16 * 256; e += 512) ((int*)hist)[e] = 0;
    if (tid < 16) { rowsum[tid] = 0.f; cnt[tid] = 0; }

    // A fragments: rows r0+lr, k = lk..lk+7 per step
    const unsigned short* gA = poolb + (size_t)(r0 + lr) * DD + lk;
    s16x8 af[4];
    #pragma unroll
    for (int kk = 0; kk < 4; kk++) af[kk] = *(const s16x8*)(gA + kk * 32);

    f32x4 acc[32];
    #pragma unroll
    for (int ct = 0; ct < 32; ct++) {
        int c = (w << 9) + (ct << 4) + lr;
        const unsigned short* gB = poolb + (size_t)c * DD + lk;
        s16x8 b0 = *(const s16x8*)(gB);
        s16x8 b1 = *(const s16x8*)(gB + 32);
        s16x8 b2 = *(const s16x8*)(gB + 64);
        s16x8 b3 = *(const s16x8*)(gB + 96);
        f32x4 a = {0.f, 0.f, 0.f, 0.f};
        a = __builtin_amdgcn_mfma_f32_16x16x32_bf16(af[0], b0, a, 0, 0, 0);
        a = __builtin_amdgcn_mfma_f32_16x16x32_bf16(af[1], b1, a, 0, 0, 0);
        a = __builtin_amdgcn_mfma_f32_16x16x32_bf16(af[2], b2, a, 0, 0, 0);
        a = __builtin_amdgcn_mfma_f32_16x16x32_bf16(af[3], b3, a, 0, 0, 0);
        acc[ct] = a;
    }
    __syncthreads();   // LDS zero visible

    // expsum + refl/posd + hist1(key[31:24])
    float es0 = 0.f, es1 = 0.f, es2 = 0.f, es3 = 0.f;
    #pragma unroll
    for (int ct = 0; ct < 32; ct++) {
        int c = (w << 9) + (ct << 4) + lr;
        float v0 = acc[ct][0], v1 = acc[ct][1], v2 = acc[ct][2], v3 = acc[ct][3];
        es0 += expf(2.f * v0); es1 += expf(2.f * v1);
        es2 += expf(2.f * v2); es3 += expf(2.f * v3);
        atomicAdd(&hist[rq4 + 0][fkey(v0) >> 24], 1);
        atomicAdd(&hist[rq4 + 1][fkey(v1) >> 24], 1);
        atomicAdd(&hist[rq4 + 2][fkey(v2) >> 24], 1);
        atomicAdd(&hist[rq4 + 3][fkey(v3) >> 24], 1);
        int rg0 = r0 + rq4;
        if (c == rg0 + 0) refl[c] = v0;
        if (c == rg0 + 1) refl[c] = v1;
        if (c == rg0 + 2) refl[c] = v2;
        if (c == rg0 + 3) refl[c] = v3;
        if (c == ((rg0 + 0) ^ NN)) posd[c ^ NN] = v0;
        if (c == ((rg0 + 1) ^ NN)) posd[c ^ NN] = v1;
        if (c == ((rg0 + 2) ^ NN)) posd[c ^ NN] = v2;
        if (c == ((rg0 + 3) ^ NN)) posd[c ^ NN] = v3;
    }
    #pragma unroll
    for (int mask = 1; mask < 16; mask <<= 1) {
        es0 += __shfl_xor(es0, mask); es1 += __shfl_xor(es1, mask);
        es2 += __shfl_xor(es2, mask); es3 += __shfl_xor(es3, mask);
    }
    if (lr == 0) {
        atomicAdd(&rowsum[rq4 + 0], es0);
        atomicAdd(&rowsum[rq4 + 1], es1);
        atomicAdd(&rowsum[rq4 + 2], es2);
        atomicAdd(&rowsum[rq4 + 3], es3);
    }
    __syncthreads();
    if (tid < 16) negsum[r0 + tid] = rowsum[tid];

    // scan1: wave w scans rows 2w, 2w+1
    #pragma unroll
    for (int q = 0; q < 2; q++) {
        int rr = 2 * w + q;
        int4 h4 = ((const int4*)hist[rr])[l];
        int s = h4.x + h4.y + h4.z + h4.w;
        int suf = s;
        #pragma unroll
        for (int off = 1; off < 64; off <<= 1) {
            int x = __shfl_down(suf, off);
            if (l + off < 64) suf += x;
        }
        int A = suf - s;
        int ca3 = A, ca2 = A + h4.w, ca1 = ca2 + h4.z, ca0 = ca1 + h4.y;
        if (ca3 < THR && THR <= ca3 + h4.w) { rowB[rr] = 4 * l + 3; rowCum[rr] = ca3; }
        if (ca2 < THR && THR <= ca2 + h4.z) { rowB[rr] = 4 * l + 2; rowCum[rr] = ca2; }
        if (ca1 < THR && THR <= ca1 + h4.y) { rowB[rr] = 4 * l + 1; rowCum[rr] = ca1; }
        if (ca0 < THR && THR <= ca0 + h4.x) { rowB[rr] = 4 * l + 0; rowCum[rr] = ca0; }
    }
    __syncthreads();

    int B0 = rowB[rq4 + 0], B1 = rowB[rq4 + 1], B2 = rowB[rq4 + 2], B3 = rowB[rq4 + 3];
    for (int e = tid; e < 16 * 256; e += 512) ((int*)hist)[e] = 0;
    __syncthreads();

    // hist2 on key[23:16] within selected top bin
    #pragma unroll
    for (int ct = 0; ct < 32; ct++) {
        unsigned k0 = fkey(acc[ct][0]), k1 = fkey(acc[ct][1]);
        unsigned k2 = fkey(acc[ct][2]), k3 = fkey(acc[ct][3]);
        if ((int)(k0 >> 24) == B0) atomicAdd(&hist[rq4 + 0][(k0 >> 16) & 255], 1);
        if ((int)(k1 >> 24) == B1) atomicAdd(&hist[rq4 + 1][(k1 >> 16) & 255], 1);
        if ((int)(k2 >> 24) == B2) atomicAdd(&hist[rq4 + 2][(k2 >> 16) & 255], 1);
        if ((int)(k3 >> 24) == B3) atomicAdd(&hist[rq4 + 3][(k3 >> 16) & 255], 1);
    }
    __syncthreads();

    // scan2
    #pragma unroll
    for (int q = 0; q < 2; q++) {
        int rr = 2 * w + q;
        int base = rowCum[rr];
        int4 h4 = ((const int4*)hist[rr])[l];
        int s = h4.x + h4.y + h4.z + h4.w;
        int suf = s;
        #pragma unroll
        for (int off = 1; off < 64; off <<= 1) {
            int x = __shfl_down(suf, off);
            if (l + off < 64) suf += x;
        }
        int A = base + suf - s;
        int ca3 = A, ca2 = A + h4.w, ca1 = ca2 + h4.z, ca0 = ca1 + h4.y;
        if (ca3 < THR && THR <= ca3 + h4.w) rowP16[rr] = (rowB[rr] << 8) | (4 * l + 3);
        if (ca2 < THR && THR <= ca2 + h4.z) rowP16[rr] = (rowB[rr] << 8) | (4 * l + 2);
        if (ca1 < THR && THR <= ca1 + h4.y) rowP16[rr] = (rowB[rr] << 8) | (4 * l + 1);
        if (ca0 < THR && THR <= ca0 + h4.x) rowP16[rr] = (rowB[rr] << 8) | (4 * l + 0);
    }
    __syncthreads();

    unsigned P0 = (unsigned)rowP16[rq4 + 0], P1 = (unsigned)rowP16[rq4 + 1];
    unsigned P2 = (unsigned)rowP16[rq4 + 2], P3 = (unsigned)rowP16[rq4 + 3];

    // collect candidates (key16 >= threshold prefix)
    #pragma unroll
    for (int ct = 0; ct < 32; ct++) {
        int c = (w << 9) + (ct << 4) + lr;
        unsigned k0 = fkey(acc[ct][0]), k1 = fkey(acc[ct][1]);
        unsigned k2 = fkey(acc[ct][2]), k3 = fkey(acc[ct][3]);
        if ((k0 >> 16) >= P0) { int p = atomicAdd(&cnt[rq4 + 0], 1); if (p < CAP) cand[rq4 + 0][p] = make_uint2(k0, (unsigned)c); }
        if ((k1 >> 16) >= P1) { int p = atomicAdd(&cnt[rq4 + 1], 1); if (p < CAP) cand[rq4 + 1][p] = make_uint2(k1, (unsigned)c); }
        if ((k2 >> 16) >= P2) { int p = atomicAdd(&cnt[rq4 + 2], 1); if (p < CAP) cand[rq4 + 2][p] = make_uint2(k2, (unsigned)c); }
        if ((k3 >> 16) >= P3) { int p = atomicAdd(&cnt[rq4 + 3], 1); if (p < CAP) cand[rq4 + 3][p] = make_uint2(k3, (unsigned)c); }
    }
    __syncthreads();

    // rank (key desc, col asc); wave w ranks rows 2w, 2w+1
    #pragma unroll
    for (int q = 0; q < 2; q++) {
        int rr = 2 * w + q;
        int C = min(cnt[rr], CAP);
        int rg = r0 + rr;
        unsigned km[5]; int im[5], rk[5];
        #pragma unroll
        for (int o = 0; o < 5; o++) {
            int b = l + o * 64;
            bool v = (b < C);
            uint2 cd = v ? cand[rr][b] : make_uint2(0u, 0u);
            km[o] = cd.x; im[o] = (int)cd.y; rk[o] = v ? 0 : (THR + CAP);
        }
        for (int c = 0; c < C; c++) {
            uint2 cd = cand[rr][c];
            unsigned kc = cd.x; int ic = (int)cd.y;
            #pragma unroll
            for (int o = 0; o < 5; o++)
                rk[o] += (kc > km[o] || (kc == km[o] && ic < im[o])) ? 1 : 0;
        }
        #pragma unroll
        for (int o = 0; o < 5; o++)
            if (rk[o] < THR) topidx[(size_t)rg * THR + rk[o]] = im[o];
    }
}

// ---------------- mix (via linearity) + normalize + dot + loss; t-pair unrolled ----------------
__global__ __launch_bounds__(256, 4) void mixloss(
    const float* __restrict__ P, const float* __restrict__ pool_n,
    const float* __restrict__ proj_b,
    const float* __restrict__ negsum, const float* __restrict__ refl,
    const float* __restrict__ posd, const int* __restrict__ topidx,
    const int* __restrict__ idx1, const int* __restrict__ idx2,
    float* __restrict__ out) {
    __shared__ int top_sh[THR];
    __shared__ int idx_sh[2 * SS];
    __shared__ float red2[4];

    int tid = threadIdx.x, w = tid >> 6, l = tid & 63;
    int r = blockIdx.x;
    int i = r & (NN - 1);
    const int* idxp = ((r >= NN) ? idx2 : idx1) + (size_t)i * (2 * SS);

    if (tid < THR) top_sh[tid] = topidx[(size_t)r * THR + tid];
    for (int e = tid; e < 2 * SS; e += 256) idx_sh[e] = idxp[e];
    __syncthreads();

    int g = l >> 4, sub = l & 15, d0 = sub * 8;
    float4 qa = *(const float4*)(pool_n + (size_t)r * DD + d0);
    float4 qb = *(const float4*)(pool_n + (size_t)r * DD + d0 + 4);
    float4 ba = *(const float4*)(proj_b + d0);
    float4 bb = *(const float4*)(proj_b + d0 + 4);

    float wsum = 0.f;
    // 75 pairs of t; pair p handled by 16-lane group: p = it*4 + g, it = w, w+4, ..., <19
    for (int it = w; it < 19; it += 4) {
        int p = it * 4 + g;
        if (p < 75) {
            int t = 2 * p;
            int c1a = top_sh[idx_sh[t]],     c2a = top_sh[idx_sh[t + SS]];
            int c1b = top_sh[idx_sh[t + 1]], c2b = top_sh[idx_sh[t + 1 + SS]];
            const float* pa1 = P + (size_t)c1a * DD + d0;
            const float* pa2 = P + (size_t)c2a * DD + d0;
            const float* pb1 = P + (size_t)c1b * DD + d0;
            const float* pb2 = P + (size_t)c2b * DD + d0;
            float4 xa0 = *(const float4*)pa1;
            float4 xa1 = *(const float4*)(pa1 + 4);
            float4 ya0 = *(const float4*)pa2;
            float4 ya1 = *(const float4*)(pa2 + 4);
            float4 xb0 = *(const float4*)pb1;
            float4 xb1 = *(const float4*)(pb1 + 4);
            float4 yb0 = *(const float4*)pb2;
            float4 yb1 = *(const float4*)(pb2 + 4);

            float a0 = fmaf(0.2f, xa0.x, fmaf(0.8f, ya0.x, ba.x));
            float a1 = fmaf(0.2f, xa0.y, fmaf(0.8f, ya0.y, ba.y));
            float a2 = fmaf(0.2f, xa0.z, fmaf(0.8f, ya0.z, ba.z));
            float a3 = fmaf(0.2f, xa0.w, fmaf(0.8f, ya0.w, ba.w));
            float a4 = fmaf(0.2f, xa1.x, fmaf(0.8f, ya1.x, bb.x));
            float a5 = fmaf(0.2f, xa1.y, fmaf(0.8f, ya1.y, bb.y));
            float a6 = fmaf(0.2f, xa1.z, fmaf(0.8f, ya1.z, bb.z));
            float a7 = fmaf(0.2f, xa1.w, fmaf(0.8f, ya1.w, bb.w));
            float b0 = fmaf(0.2f, xb0.x, fmaf(0.8f, yb0.x, ba.x));
            float b1 = fmaf(0.2f, xb0.y, fmaf(0.8f, yb0.y, ba.y));
            float b2 = fmaf(0.2f, xb0.z, fmaf(0.8f, yb0.z, ba.z));
            float b3 = fmaf(0.2f, xb0.w, fmaf(0.8f, yb0.w, ba.w));
            float b4 = fmaf(0.2f, xb1.x, fmaf(0.8f, yb1.x, bb.x));
            float b5 = fmaf(0.2f, xb1.y, fmaf(0.8f, yb1.y, bb.y));
            float b6 = fmaf(0.2f, xb1.z, fmaf(0.8f, yb1.z, bb.z));
            float b7 = fmaf(0.2f, xb1.w, fmaf(0.8f, yb1.w, bb.w));

            float n2a = a0*a0 + a1*a1 + a2*a2 + a3*a3 + a4*a4 + a5*a5 + a6*a6 + a7*a7;
            float dta = a0*qa.x + a1*qa.y + a2*qa.z + a3*qa.w
                      + a4*qb.x + a5*qb.y + a6*qb.z + a7*qb.w;
            float n2b = b0*b0 + b1*b1 + b2*b2 + b3*b3 + b4*b4 + b5*b5 + b6*b6 + b7*b7;
            float dtb = b0*qa.x + b1*qa.y + b2*qa.z + b3*qa.w
                      + b4*qb.x + b5*qb.y + b6*qb.z + b7*qb.w;
            #pragma unroll
            for (int mask = 1; mask < 16; mask <<= 1) {
                n2a += __shfl_xor(n2a, mask);
                dta += __shfl_xor(dta, mask);
                n2b += __shfl_xor(n2b, mask);
                dtb += __shfl_xor(dtb, mask);
            }
            float ea = expf(2.0f * dta * rsqrtf(fmaxf(n2a, 1e-24f)));
            float eb = expf(2.0f * dtb * rsqrtf(fmaxf(n2b, 1e-24f)));
            wsum += (sub == 0) ? (ea + eb) : 0.f;
        }
    }
    #pragma unroll
    for (int mask = 1; mask < 64; mask <<= 1) wsum += __shfl_xor(wsum, mask);
    if (l == 0) red2[w] = wsum;
    __syncthreads();
    if (tid == 0) {
        float negm = red2[0] + red2[1] + red2[2] + red2[3];
        float den = negsum[r] + negm - refl[r];
        float loss = logf(den) - 2.0f * posd[r];
        atomicAdd(out, loss * (1.0f / 4096.0f));
    }
}

extern "C" void kernel_launch(void* const* d_in, const int* in_sizes, int n_in,
                              void* d_out, int out_size, void* d_ws, size_t ws_size,
                              hipStream_t stream) {
    const float* z1  = (const float*)d_in[0];
    const float* z2  = (const float*)d_in[1];
    const float* pw  = (const float*)d_in[2];
    const float* pb  = (const float*)d_in[3];
    const int* idx1  = (const int*)d_in[4];
    const int* idx2  = (const int*)d_in[5];
    float* out = (float*)d_out;

    float* wsf = (float*)d_ws;
    float* pool_n  = wsf + OFF_POOLN;
    float* wtT     = wsf + OFF_WTT;
    float* Pm      = wsf + OFF_PROJ;
    float* negs    = wsf + OFF_NEG;
    float* rfl     = wsf + OFF_REFL;
    float* psd     = wsf + OFF_POSD;
    int*   topi    = (int*)(wsf + OFF_TOPI);
    unsigned short* poolb = (unsigned short*)(wsf + OFF_POOLB);

    hipMemsetAsync(d_out, 0, sizeof(float), stream);

    prep_norm<<<PP, 64, 0, stream>>>(z1, z2, pool_n, poolb);
    prep_wt<<<64, 256, 0, stream>>>(pw, wtT);
    prep_proj<<<PP / 8, 256, 0, stream>>>(z1, z2, wtT, Pm);
    gramsel<<<PP / 16, 512, 0, stream>>>(poolb, negs, rfl, psd, topi);
    mixloss<<<PP, 256, 0, stream>>>(Pm, pool_n, pb, negs, rfl, psd, topi,
                                    idx1, idx2, out);
}

// Round 7
// 164.712 us; speedup vs baseline: 1.3871x; 1.3871x over previous
//
#include <hip/hip_runtime.h>
#include <math.h>

#define NN 2048
#define PP 4096
#define DD 128
#define SS 150
#define THR 204
#define ROWS 8
#define TPB 512
#define CAP 512
#define EXP2C 2.8853900817779268f   // 2/ln(2): exp(2x) = 2^(EXP2C*x)

typedef float f32x4 __attribute__((ext_vector_type(4)));
typedef short s16x8 __attribute__((ext_vector_type(8)));

// ws layout (float offsets)
#define OFF_POOLN 0
#define OFF_POOLT 524288
#define OFF_WTT   1048576   // 16384 floats (W^T, [k][d])
#define OFF_PROJ  1064960   // 4096*128 floats = z_pool @ W^T
#define OFF_NEG   1589248
#define OFF_REFL  1593344
#define OFF_POSD  1597440
#define OFF_TOPI  1601536   // 4096*204 ints
#define OFF_POOLB 2437120   // 4096*128 bf16 (ushort) = 262144 floats
#define OFF_SIMS  2699264   // 4096*4096 fp32 = 64 MB
#define WS_FAST_FLOATS (OFF_SIMS + (size_t)PP * PP)

// ---------------- prep: normalize pool rows; fp32 row-major + fp32 transposed + bf16 ----------------
__global__ void prep_norm(const float* __restrict__ z1, const float* __restrict__ z2,
                          float* __restrict__ pool_n, float* __restrict__ pool_nT,
                          unsigned short* __restrict__ poolb) {
    int b = blockIdx.x;          // pool row 0..4095
    int l = threadIdx.x;         // 0..63
    const float* src = (b < NN) ? z1 + (size_t)b * DD : z2 + (size_t)(b - NN) * DD;
    float2 v = *(const float2*)(src + 2 * l);
    float ss = v.x * v.x + v.y * v.y;
    #pragma unroll
    for (int mask = 1; mask < 64; mask <<= 1) ss += __shfl_xor(ss, mask);
    float inv = 1.0f / fmaxf(sqrtf(ss), 1e-12f);
    float2 nv; nv.x = v.x * inv; nv.y = v.y * inv;
    *(float2*)(pool_n + (size_t)b * DD + 2 * l) = nv;
    pool_nT[(size_t)(2 * l) * PP + b]     = nv.x;
    pool_nT[(size_t)(2 * l + 1) * PP + b] = nv.y;
    // bf16 RNE pack
    unsigned ux = __float_as_uint(nv.x); ux = (ux + 0x7FFFu + ((ux >> 16) & 1u)) >> 16;
    unsigned uy = __float_as_uint(nv.y); uy = (uy + 0x7FFFu + ((uy >> 16) & 1u)) >> 16;
    ((unsigned*)poolb)[(size_t)b * 64 + l] = ux | (uy << 16);
}

// ---------------- prep: transpose proj_w (fp32), layout [k][d] ----------------
__global__ void prep_wt(const float* __restrict__ pw, float* __restrict__ wtT) {
    int e = blockIdx.x * 256 + threadIdx.x;   // 0..16383
    int k = e >> 7, d = e & 127;
    wtT[e] = pw[d * DD + k];
}

// ---------------- prep: P = z_pool @ W^T (no bias) ----------------
__global__ __launch_bounds__(256, 4) void prep_proj(
    const float* __restrict__ z1, const float* __restrict__ z2,
    const float* __restrict__ wtT, float* __restrict__ P) {
    __shared__ float z_sh[8][DD];
    int tid = threadIdx.x;
    int r0 = blockIdx.x * 8;
    for (int e = tid; e < 8 * DD; e += 256) {
        int rr = r0 + (e >> 7);
        z_sh[e >> 7][e & 127] = (rr < NN) ? z1[(size_t)rr * DD + (e & 127)]
                                          : z2[(size_t)(rr - NN) * DD + (e & 127)];
    }
    __syncthreads();
    int d = tid & 127, h = tid >> 7;
    float a0 = 0.f, a1 = 0.f, a2 = 0.f, a3 = 0.f;
    for (int k = 0; k < DD; k++) {
        float wv = wtT[k * DD + d];
        a0 += z_sh[4 * h + 0][k] * wv;
        a1 += z_sh[4 * h + 1][k] * wv;
        a2 += z_sh[4 * h + 2][k] * wv;
        a3 += z_sh[4 * h + 3][k] * wv;
    }
    P[(size_t)(r0 + 4 * h + 0) * DD + d] = a0;
    P[(size_t)(r0 + 4 * h + 1) * DD + d] = a1;
    P[(size_t)(r0 + 4 * h + 2) * DD + d] = a2;
    P[(size_t)(r0 + 4 * h + 3) * DD + d] = a3;
}

// order-preserving float->uint key (larger float => larger key)
__device__ __forceinline__ unsigned fkey(float v) {
    unsigned u = __float_as_uint(v);
    return u ^ (unsigned)(((int)u >> 31) | 0x80000000);
}

// ---------------- FAST PATH A: sims = poolb @ poolb^T via MFMA, fp32 out ----------------
// 256 thr / 4 waves; block tile 128x128; wave tile 64x64 = 4x4 frags of 16x16; K=128 in 4 steps.
#define LDA 136   // shorts per LDS row (128 + 8 pad -> 272 B stride, 2-way bank alias only)
__global__ __launch_bounds__(256) void gram_mfma(
    const unsigned short* __restrict__ poolb, float* __restrict__ sims) {
    __shared__ short tiles[2 * 128 * LDA];   // 69.6 KB
    short* As = tiles;
    short* Bs = tiles + 128 * LDA;

    int tid = threadIdx.x;
    int bi = blockIdx.x >> 5, bj = blockIdx.x & 31;
    int r0 = bi * 128, c0 = bj * 128;

    const unsigned short* gA = poolb + (size_t)r0 * DD;
    const unsigned short* gB = poolb + (size_t)c0 * DD;
    #pragma unroll
    for (int it = 0; it < 8; it++) {
        int g = it * 256 + tid;              // 16-byte chunk id, 2048 chunks per tile
        int row = g >> 4, ch = (g & 15) * 8; // short offsets
        *(s16x8*)&As[row * LDA + ch] = *(const s16x8*)(gA + row * DD + ch);
        *(s16x8*)&Bs[row * LDA + ch] = *(const s16x8*)(gB + row * DD + ch);
    }
    __syncthreads();

    int l = tid & 63, w = tid >> 6;
    int wr = (w >> 1) * 64, wc = (w & 1) * 64;
    int lr = l & 15, lk = (l >> 4) * 8;

    f32x4 zero = {0.f, 0.f, 0.f, 0.f};
    f32x4 acc[4][4];
    #pragma unroll
    for (int m = 0; m < 4; m++)
        #pragma unroll
        for (int n = 0; n < 4; n++) acc[m][n] = zero;

    #pragma unroll
    for (int kk = 0; kk < 4; kk++) {
        int ko = kk * 32 + lk;
        s16x8 av[4], bv[4];
        #pragma unroll
        for (int m = 0; m < 4; m++)
            av[m] = *(const s16x8*)&As[(wr + m * 16 + lr) * LDA + ko];
        #pragma unroll
        for (int n = 0; n < 4; n++)
            bv[n] = *(const s16x8*)&Bs[(wc + n * 16 + lr) * LDA + ko];
        #pragma unroll
        for (int m = 0; m < 4; m++)
            #pragma unroll
            for (int n = 0; n < 4; n++)
                acc[m][n] = __builtin_amdgcn_mfma_f32_16x16x32_bf16(av[m], bv[n], acc[m][n], 0, 0, 0);
    }

    // C write: row = (l>>4)*4 + reg, col = l&15 within each 16x16 frag
    int fq = (l >> 4) * 4, fr = l & 15;
    #pragma unroll
    for (int m = 0; m < 4; m++)
        #pragma unroll
        for (int n = 0; n < 4; n++) {
            size_t base = (size_t)(r0 + wr + m * 16 + fq) * PP + (c0 + wc + n * 16 + fr);
            #pragma unroll
            for (int reg = 0; reg < 4; reg++)
                sims[base + (size_t)reg * PP] = acc[m][n][reg];
        }
}

// ---------------- FAST PATH B: per-row expsum + refl/posd + top-204 select ----------------
__global__ __launch_bounds__(256) void rowselect(
    const float* __restrict__ sims,
    float* __restrict__ negsum, float* __restrict__ refl, float* __restrict__ posd,
    int* __restrict__ topidx) {
    __shared__ int hist[256];
    __shared__ uint2 cand[CAP];
    __shared__ float part[4];
    __shared__ int scal[4];   // 0:B  1:cum  2:P16  3:cnt

    int tid = threadIdx.x, w = tid >> 6, l = tid & 63;
    int r = blockIdx.x;
    const float4* rp = (const float4*)(sims + (size_t)r * PP);

    float4 va[4];
    float es = 0.f;
    #pragma unroll
    for (int j = 0; j < 4; j++) {
        va[j] = rp[tid + j * 256];
        es += __builtin_exp2f(EXP2C * va[j].x) + __builtin_exp2f(EXP2C * va[j].y)
            + __builtin_exp2f(EXP2C * va[j].z) + __builtin_exp2f(EXP2C * va[j].w);
    }
    #pragma unroll
    for (int mask = 1; mask < 64; mask <<= 1) es += __shfl_xor(es, mask);
    if (l == 0) part[w] = es;

    hist[tid] = 0;
    if (tid == 0) scal[3] = 0;
    // refl / posd: the thread owning that column writes it
    #pragma unroll
    for (int j = 0; j < 4; j++) {
        int col0 = (tid + j * 256) * 4;
        #pragma unroll
        for (int c = 0; c < 4; c++) {
            float v = (c == 0) ? va[j].x : (c == 1) ? va[j].y : (c == 2) ? va[j].z : va[j].w;
            if (col0 + c == r) refl[r] = v;
            if (col0 + c == (r ^ NN)) posd[r] = v;
        }
    }
    __syncthreads();
    if (tid == 0) negsum[r] = part[0] + part[1] + part[2] + part[3];

    // hist1 on key[31:24]
    #pragma unroll
    for (int j = 0; j < 4; j++) {
        atomicAdd(&hist[fkey(va[j].x) >> 24], 1);
        atomicAdd(&hist[fkey(va[j].y) >> 24], 1);
        atomicAdd(&hist[fkey(va[j].z) >> 24], 1);
        atomicAdd(&hist[fkey(va[j].w) >> 24], 1);
    }
    __syncthreads();
    if (w == 0) {
        int4 h4 = ((const int4*)hist)[l];
        int s = h4.x + h4.y + h4.z + h4.w;
        int suf = s;
        #pragma unroll
        for (int off = 1; off < 64; off <<= 1) {
            int x = __shfl_down(suf, off);
            if (l + off < 64) suf += x;
        }
        int A = suf - s;
        int ca3 = A, ca2 = A + h4.w, ca1 = ca2 + h4.z, ca0 = ca1 + h4.y;
        if (ca3 < THR && THR <= ca3 + h4.w) { scal[0] = 4 * l + 3; scal[1] = ca3; }
        if (ca2 < THR && THR <= ca2 + h4.z) { scal[0] = 4 * l + 2; scal[1] = ca2; }
        if (ca1 < THR && THR <= ca1 + h4.y) { scal[0] = 4 * l + 1; scal[1] = ca1; }
        if (ca0 < THR && THR <= ca0 + h4.x) { scal[0] = 4 * l + 0; scal[1] = ca0; }
    }
    __syncthreads();
    int B = scal[0], base = scal[1];
    hist[tid] = 0;
    __syncthreads();

    // hist2 on key[23:16] within bin B
    #pragma unroll
    for (int j = 0; j < 4; j++) {
        #pragma unroll
        for (int c = 0; c < 4; c++) {
            float v = (c == 0) ? va[j].x : (c == 1) ? va[j].y : (c == 2) ? va[j].z : va[j].w;
            unsigned key = fkey(v);
            if ((int)(key >> 24) == B) atomicAdd(&hist[(key >> 16) & 255], 1);
        }
    }
    __syncthreads();
    if (w == 0) {
        int4 h4 = ((const int4*)hist)[l];
        int s = h4.x + h4.y + h4.z + h4.w;
        int suf = s;
        #pragma unroll
        for (int off = 1; off < 64; off <<= 1) {
            int x = __shfl_down(suf, off);
            if (l + off < 64) suf += x;
        }
        int A = base + suf - s;
        int ca3 = A, ca2 = A + h4.w, ca1 = ca2 + h4.z, ca0 = ca1 + h4.y;
        if (ca3 < THR && THR <= ca3 + h4.w) scal[2] = (B << 8) | (4 * l + 3);
        if (ca2 < THR && THR <= ca2 + h4.z) scal[2] = (B << 8) | (4 * l + 2);
        if (ca1 < THR && THR <= ca1 + h4.y) scal[2] = (B << 8) | (4 * l + 1);
        if (ca0 < THR && THR <= ca0 + h4.x) scal[2] = (B << 8) | (4 * l + 0);
    }
    __syncthreads();
    unsigned P16 = (unsigned)scal[2];

    // collect candidates
    #pragma unroll
    for (int j = 0; j < 4; j++) {
        int col0 = (tid + j * 256) * 4;
        #pragma unroll
        for (int c = 0; c < 4; c++) {
            float v = (c == 0) ? va[j].x : (c == 1) ? va[j].y : (c == 2) ? va[j].z : va[j].w;
            unsigned key = fkey(v);
            if ((key >> 16) >= P16) {
                int p = atomicAdd(&scal[3], 1);
                if (p < CAP) cand[p] = make_uint2(key, (unsigned)(col0 + c));
            }
        }
    }
    __syncthreads();

    // rank (key desc, col asc)
    int C = min(scal[3], CAP);
    #pragma unroll
    for (int o = 0; o < 2; o++) {
        int t = tid + o * 256;
        if (t < C) {
            uint2 me = cand[t];
            int rk = 0;
            for (int c = 0; c < C; c++) {
                uint2 cd = cand[c];
                rk += (cd.x > me.x || (cd.x == me.x && (int)cd.y < (int)me.y)) ? 1 : 0;
            }
            if (rk < THR) topidx[(size_t)r * THR + rk] = (int)me.y;
        }
    }
}

// ---------------- FALLBACK: round-4 fused gram+select (used if ws too small) ----------------
__global__ __launch_bounds__(TPB, 4) void simtopk(
    const float* __restrict__ pool_n, const float* __restrict__ pool_nT,
    float* __restrict__ negsum, float* __restrict__ refl, float* __restrict__ posd,
    int* __restrict__ topidx) {
    __shared__ float q_sh[ROWS][DD];
    __shared__ int hist[ROWS][256];
    __shared__ uint2 cand[ROWS][CAP];
    __shared__ int rowB[ROWS], rowCum[ROWS], rowP[ROWS], cnt[ROWS];
    __shared__ float partial[ROWS][8];

    int tid = threadIdx.x, w = tid >> 6, l = tid & 63;
    int r0 = blockIdx.x * ROWS;

    for (int e = tid; e < ROWS * DD; e += TPB)
        q_sh[e >> 7][e & 127] = pool_n[(size_t)r0 * DD + e];
    __syncthreads();

    float acc[ROWS][8];
    #pragma unroll
    for (int r = 0; r < ROWS; r++)
        #pragma unroll
        for (int e = 0; e < 8; e++) acc[r][e] = 0.f;

    const float4* pt4 = (const float4*)pool_nT;
    for (int k = 0; k < DD; k++) {
        float4 p0 = pt4[k * 1024 + tid];
        float4 p1 = pt4[k * 1024 + 512 + tid];
        #pragma unroll
        for (int r = 0; r < ROWS; r++) {
            float qk = q_sh[r][k];
            acc[r][0] += qk * p0.x; acc[r][1] += qk * p0.y; acc[r][2] += qk * p0.z; acc[r][3] += qk * p0.w;
            acc[r][4] += qk * p1.x; acc[r][5] += qk * p1.y; acc[r][6] += qk * p1.z; acc[r][7] += qk * p1.w;
        }
    }

    #pragma unroll
    for (int r = 0; r < ROWS; r++) {
        int rg = r0 + r;
        float es = 0.f;
        #pragma unroll
        for (int e = 0; e < 8; e++) {
            es += __builtin_exp2f(EXP2C * acc[r][e]);
            int col = (e >> 2) * 2048 + (tid << 2) + (e & 3);
            if (col == rg) refl[rg] = acc[r][e];
            if (col == (rg ^ NN)) posd[rg] = acc[r][e];
        }
        #pragma unroll
        for (int mask = 1; mask < 64; mask <<= 1) es += __shfl_xor(es, mask);
        if (l == 0) partial[r][w] = es;
    }

    for (int e = tid; e < ROWS * 256; e += TPB) ((int*)hist)[e] = 0;
    if (tid < ROWS) cnt[tid] = 0;
    __syncthreads();
    if (tid < ROWS) {
        float s = 0.f;
        #pragma unroll
        for (int ww = 0; ww < 8; ww++) s += partial[tid][ww];
        negsum[r0 + tid] = s;
    }
    #pragma unroll
    for (int r = 0; r < ROWS; r++)
        #pragma unroll
        for (int e = 0; e < 8; e++)
            atomicAdd(&hist[r][fkey(acc[r][e]) >> 24], 1);
    __syncthreads();

    {
        int rr = w;
        int4 h4 = ((const int4*)hist[rr])[l];
        int s = h4.x + h4.y + h4.z + h4.w;
        int suf = s;
        #pragma unroll
        for (int off = 1; off < 64; off <<= 1) {
            int x = __shfl_down(suf, off);
            if (l + off < 64) suf += x;
        }
        int A = suf - s;
        int ca3 = A, ca2 = A + h4.w, ca1 = ca2 + h4.z, ca0 = ca1 + h4.y;
        if (ca3 < THR && THR <= ca3 + h4.w) { rowB[rr] = 4 * l + 3; rowCum[rr] = ca3; }
        if (ca2 < THR && THR <= ca2 + h4.z) { rowB[rr] = 4 * l + 2; rowCum[rr] = ca2; }
        if (ca1 < THR && THR <= ca1 + h4.y) { rowB[rr] = 4 * l + 1; rowCum[rr] = ca1; }
        if (ca0 < THR && THR <= ca0 + h4.x) { rowB[rr] = 4 * l + 0; rowCum[rr] = ca0; }
    }
    __syncthreads();

    for (int e = tid; e < ROWS * 256; e += TPB) ((int*)hist)[e] = 0;
    __syncthreads();
    #pragma unroll
    for (int r = 0; r < ROWS; r++) {
        int B = rowB[r];
        #pragma unroll
        for (int e = 0; e < 8; e++) {
            unsigned key = fkey(acc[r][e]);
            if ((int)(key >> 24) == B) atomicAdd(&hist[r][(key >> 16) & 255], 1);
        }
    }
    __syncthreads();

    {
        int rr = w;
        int base = rowCum[rr];
        int4 h4 = ((const int4*)hist[rr])[l];
        int s = h4.x + h4.y + h4.z + h4.w;
        int suf = s;
        #pragma unroll
        for (int off = 1; off < 64; off <<= 1) {
            int x = __shfl_down(suf, off);
            if (l + off < 64) suf += x;
        }
        int A = base + suf - s;
        int ca3 = A, ca2 = A + h4.w, ca1 = ca2 + h4.z, ca0 = ca1 + h4.y;
        if (ca3 < THR && THR <= ca3 + h4.w) rowP[rr] = (rowB[rr] << 8) | (4 * l + 3);
        if (ca2 < THR && THR <= ca2 + h4.z) rowP[rr] = (rowB[rr] << 8) | (4 * l + 2);
        if (ca1 < THR && THR <= ca1 + h4.y) rowP[rr] = (rowB[rr] << 8) | (4 * l + 1);
        if (ca0 < THR && THR <= ca0 + h4.x) rowP[rr] = (rowB[rr] << 8) | (4 * l + 0);
    }
    __syncthreads();

    #pragma unroll
    for (int r = 0; r < ROWS; r++) {
        unsigned P16 = (unsigned)rowP[r];
        #pragma unroll
        for (int e = 0; e < 8; e++) {
            unsigned key = fkey(acc[r][e]);
            if ((key >> 16) >= P16) {
                int p = atomicAdd(&cnt[r], 1);
                if (p < CAP) {
                    int col = (e >> 2) * 2048 + (tid << 2) + (e & 3);
                    cand[r][p] = make_uint2(key, (unsigned)col);
                }
            }
        }
    }
    __syncthreads();

    {
        int rr = w;
        int C = min(cnt[rr], CAP);
        int rg = r0 + rr;
        unsigned km[8]; int im[8], rk[8];
        #pragma unroll
        for (int o = 0; o < 8; o++) {
            int b = l + o * 64;
            bool v = (b < C);
            uint2 cd = v ? cand[rr][b] : make_uint2(0u, 0u);
            km[o] = cd.x; im[o] = (int)cd.y; rk[o] = v ? 0 : (THR + CAP);
        }
        for (int c = 0; c < C; c++) {
            uint2 cd = cand[rr][c];
            unsigned kc = cd.x; int ic = (int)cd.y;
            #pragma unroll
            for (int o = 0; o < 8; o++)
                if (o * 64 < C)
                    rk[o] += (kc > km[o] || (kc == km[o] && ic < im[o])) ? 1 : 0;
        }
        #pragma unroll
        for (int o = 0; o < 8; o++)
            if (rk[o] < THR) topidx[(size_t)rg * THR + rk[o]] = im[o];
    }
}

// ---------------- mix (via linearity) + normalize + dot + loss; t-pair unrolled ----------------
__global__ __launch_bounds__(256, 4) void mixloss(
    const float* __restrict__ P, const float* __restrict__ pool_n,
    const float* __restrict__ proj_b,
    const float* __restrict__ negsum, const float* __restrict__ refl,
    const float* __restrict__ posd, const int* __restrict__ topidx,
    const int* __restrict__ idx1, const int* __restrict__ idx2,
    float* __restrict__ out) {
    __shared__ int top_sh[THR];
    __shared__ int idx_sh[2 * SS];
    __shared__ float red2[4];

    int tid = threadIdx.x, w = tid >> 6, l = tid & 63;
    int r = blockIdx.x;
    int i = r & (NN - 1);
    const int* idxp = ((r >= NN) ? idx2 : idx1) + (size_t)i * (2 * SS);

    if (tid < THR) top_sh[tid] = topidx[(size_t)r * THR + tid];
    for (int e = tid; e < 2 * SS; e += 256) idx_sh[e] = idxp[e];
    __syncthreads();

    int g = l >> 4, sub = l & 15, d0 = sub * 8;
    float4 qa = *(const float4*)(pool_n + (size_t)r * DD + d0);
    float4 qb = *(const float4*)(pool_n + (size_t)r * DD + d0 + 4);
    float4 ba = *(const float4*)(proj_b + d0);
    float4 bb = *(const float4*)(proj_b + d0 + 4);

    float wsum = 0.f;
    // 75 pairs of t; pair p handled by 16-lane group: p = it*4 + g, it = w, w+4, ..., <19
    for (int it = w; it < 19; it += 4) {
        int p = it * 4 + g;
        if (p < 75) {
            int t = 2 * p;
            int c1a = top_sh[idx_sh[t]],     c2a = top_sh[idx_sh[t + SS]];
            int c1b = top_sh[idx_sh[t + 1]], c2b = top_sh[idx_sh[t + 1 + SS]];
            const float* pa1 = P + (size_t)c1a * DD + d0;
            const float* pa2 = P + (size_t)c2a * DD + d0;
            const float* pb1 = P + (size_t)c1b * DD + d0;
            const float* pb2 = P + (size_t)c2b * DD + d0;
            float4 xa0 = *(const float4*)pa1;
            float4 xa1 = *(const float4*)(pa1 + 4);
            float4 ya0 = *(const float4*)pa2;
            float4 ya1 = *(const float4*)(pa2 + 4);
            float4 xb0 = *(const float4*)pb1;
            float4 xb1 = *(const float4*)(pb1 + 4);
            float4 yb0 = *(const float4*)pb2;
            float4 yb1 = *(const float4*)(pb2 + 4);

            float a0 = fmaf(0.2f, xa0.x, fmaf(0.8f, ya0.x, ba.x));
            float a1 = fmaf(0.2f, xa0.y, fmaf(0.8f, ya0.y, ba.y));
            float a2 = fmaf(0.2f, xa0.z, fmaf(0.8f, ya0.z, ba.z));
            float a3 = fmaf(0.2f, xa0.w, fmaf(0.8f, ya0.w, ba.w));
            float a4 = fmaf(0.2f, xa1.x, fmaf(0.8f, ya1.x, bb.x));
            float a5 = fmaf(0.2f, xa1.y, fmaf(0.8f, ya1.y, bb.y));
            float a6 = fmaf(0.2f, xa1.z, fmaf(0.8f, ya1.z, bb.z));
            float a7 = fmaf(0.2f, xa1.w, fmaf(0.8f, ya1.w, bb.w));
            float b0 = fmaf(0.2f, xb0.x, fmaf(0.8f, yb0.x, ba.x));
            float b1 = fmaf(0.2f, xb0.y, fmaf(0.8f, yb0.y, ba.y));
            float b2 = fmaf(0.2f, xb0.z, fmaf(0.8f, yb0.z, ba.z));
            float b3 = fmaf(0.2f, xb0.w, fmaf(0.8f, yb0.w, ba.w));
            float b4 = fmaf(0.2f, xb1.x, fmaf(0.8f, yb1.x, bb.x));
            float b5 = fmaf(0.2f, xb1.y, fmaf(0.8f, yb1.y, bb.y));
            float b6 = fmaf(0.2f, xb1.z, fmaf(0.8f, yb1.z, bb.z));
            float b7 = fmaf(0.2f, xb1.w, fmaf(0.8f, yb1.w, bb.w));

            float n2a = a0*a0 + a1*a1 + a2*a2 + a3*a3 + a4*a4 + a5*a5 + a6*a6 + a7*a7;
            float dta = a0*qa.x + a1*qa.y + a2*qa.z + a3*qa.w
                      + a4*qb.x + a5*qb.y + a6*qb.z + a7*qb.w;
            float n2b = b0*b0 + b1*b1 + b2*b2 + b3*b3 + b4*b4 + b5*b5 + b6*b6 + b7*b7;
            float dtb = b0*qa.x + b1*qa.y + b2*qa.z + b3*qa.w
                      + b4*qb.x + b5*qb.y + b6*qb.z + b7*qb.w;
            #pragma unroll
            for (int mask = 1; mask < 16; mask <<= 1) {
                n2a += __shfl_xor(n2a, mask);
                dta += __shfl_xor(dta, mask);
                n2b += __shfl_xor(n2b, mask);
                dtb += __shfl_xor(dtb, mask);
            }
            float ea = __builtin_exp2f(EXP2C * dta * rsqrtf(fmaxf(n2a, 1e-24f)));
            float eb = __builtin_exp2f(EXP2C * dtb * rsqrtf(fmaxf(n2b, 1e-24f)));
            wsum += (sub == 0) ? (ea + eb) : 0.f;
        }
    }
    #pragma unroll
    for (int mask = 1; mask < 64; mask <<= 1) wsum += __shfl_xor(wsum, mask);
    if (l == 0) red2[w] = wsum;
    __syncthreads();
    if (tid == 0) {
        float negm = red2[0] + red2[1] + red2[2] + red2[3];
        float den = negsum[r] + negm - refl[r];
        float loss = logf(den) - 2.0f * posd[r];
        atomicAdd(out, loss * (1.0f / 4096.0f));
    }
}

extern "C" void kernel_launch(void* const* d_in, const int* in_sizes, int n_in,
                              void* d_out, int out_size, void* d_ws, size_t ws_size,
                              hipStream_t stream) {
    const float* z1  = (const float*)d_in[0];
    const float* z2  = (const float*)d_in[1];
    const float* pw  = (const float*)d_in[2];
    const float* pb  = (const float*)d_in[3];
    const int* idx1  = (const int*)d_in[4];
    const int* idx2  = (const int*)d_in[5];
    float* out = (float*)d_out;

    float* wsf = (float*)d_ws;
    float* pool_n  = wsf + OFF_POOLN;
    float* pool_nT = wsf + OFF_POOLT;
    float* wtT     = wsf + OFF_WTT;
    float* Pm      = wsf + OFF_PROJ;
    float* negs    = wsf + OFF_NEG;
    float* rfl     = wsf + OFF_REFL;
    float* psd     = wsf + OFF_POSD;
    int*   topi    = (int*)(wsf + OFF_TOPI);
    unsigned short* poolb = (unsigned short*)(wsf + OFF_POOLB);
    float* sims    = wsf + OFF_SIMS;

    hipMemsetAsync(d_out, 0, sizeof(float), stream);

    prep_norm<<<PP, 64, 0, stream>>>(z1, z2, pool_n, pool_nT, poolb);
    prep_wt<<<64, 256, 0, stream>>>(pw, wtT);
    prep_proj<<<PP / 8, 256, 0, stream>>>(z1, z2, wtT, Pm);

    if (ws_size >= WS_FAST_FLOATS * sizeof(float)) {
        gram_mfma<<<1024, 256, 0, stream>>>(poolb, sims);
        rowselect<<<PP, 256, 0, stream>>>(sims, negs, rfl, psd, topi);
    } else {
        simtopk<<<PP / ROWS, TPB, 0, stream>>>(pool_n, pool_nT, negs, rfl, psd, topi);
    }
    mixloss<<<PP, 256, 0, stream>>>(Pm, pool_n, pb, negs, rfl, psd, topi,
                                    idx1, idx2, out);
}